// Round 12
// baseline (188.604 us; speedup 1.0000x reference)
//
#include <hip/hip_runtime.h>
#include <hip/hip_bf16.h>
#include <stdint.h>

// Problem constants
#define PB 2
#define PS 2048
#define PD 1024
#define PH 16
#define PHD 64
#define PM (PB*PS)   // 4096 rows

typedef _Float16 half8 __attribute__((ext_vector_type(8)));
typedef _Float16 half4v __attribute__((ext_vector_type(4)));
typedef __fp16   fp16x2 __attribute__((ext_vector_type(2)));
typedef float    f32x4 __attribute__((ext_vector_type(4)));

// async global->LDS, 16B per lane; LDS dst is wave-uniform base + lane*16.
// LESSON (R10/R18): never feed MFMA fragments from STRIDED global — R18's
// 4KB-stride V loads aliased every line to one L2 channel (flash 55->139us).
// LESSON (R21): flash is NOT LDS-throughput-bound — removing the P LDS
// round-trip via permlane (conflicts 3.1M->0, -6 LDS ops/tile) was neutral.
// Keep the simple v15 form.
__device__ __forceinline__ void ld_g2l_16(const void* g, void* l) {
  __builtin_amdgcn_global_load_lds(
      (const __attribute__((address_space(1))) unsigned int*)g,
      (__attribute__((address_space(3))) unsigned int*)l, 16, 0, 0);
}

// ------------- fp32 -> fp16 convert, x and all 4 weights, one launch ------
// y=0: x (4.19M elems = 524288 half8); y=1: four 1M-elem weights -> wh slots
// q(0), k(1), v(2), g(3).
__global__ void convert_all(const float* __restrict__ x,
                            const float* __restrict__ w0, const float* __restrict__ w1,
                            const float* __restrict__ w2, const float* __restrict__ w3,
                            _Float16* __restrict__ xh, _Float16* __restrict__ wh) {
  int i = blockIdx.x * blockDim.x + threadIdx.x;
  const float* src;
  _Float16* dst;
  int idx;
  if (blockIdx.y == 0) {
    src = x; dst = xh; idx = i;
  } else {
    int wsel = i >> 17;            // 131072 half8 per weight
    idx = i & 131071;
    src = (wsel==0)?w0:(wsel==1)?w1:(wsel==2)?w2:w3;
    dst = wh + (size_t)wsel * 1048576;
  }
  float4 f0 = reinterpret_cast<const float4*>(src)[2*idx];
  float4 f1 = reinterpret_cast<const float4*>(src)[2*idx+1];
  half8 o;
  o[0]=(_Float16)f0.x; o[1]=(_Float16)f0.y; o[2]=(_Float16)f0.z; o[3]=(_Float16)f0.w;
  o[4]=(_Float16)f1.x; o[5]=(_Float16)f1.y; o[6]=(_Float16)f1.z; o[7]=(_Float16)f1.w;
  reinterpret_cast<half8*>(dst)[idx] = o;
}

// ------------------ projection GEMM: one weight per block ------------------
// R13: uniform 4-way split (z: 0=q,1=g,2=k,3=v), 128x128 tile, 1024 blocks.
// R20: (256,3) — the (256,4) cap only constrained the allocator (+3.5us).
// R22 (T1): bijective XCD swizzle. The 32 consecutive blocks sharing one
// 256KB W-panel were round-robined over 8 XCDs -> each L2 pulled its own
// copy of every panel (~8x W duplication); staging DMAs missed L2 and the
// per-K-step barrier drain exposed L3 latency. Now XCD X owns 128
// contiguous logical blocks = 4 W-panels x 32 m-tiles of one z: per-XCD W
// working set 1MB -> L2-resident after first touch. nwg=1024, 1024%8==0.
// gelu(q*g) lives in flash's Q-load (q,g stored raw f16).
// z==3 (v): epilogue LDS-transpose (reuse staging LDS) -> coalesced half8
// vT stores. LDS XOR swizzle: row r stores 16B-block b at b^((r>>1)&3).
__global__ __launch_bounds__(256, 3) void proj_gemm(
    const _Float16* __restrict__ xh, const _Float16* __restrict__ wh,
    const float* __restrict__ bqp, const float* __restrict__ bgp,
    const float* __restrict__ bkp, const float* __restrict__ bvp,
    _Float16* __restrict__ qf, _Float16* __restrict__ gf,
    _Float16* __restrict__ kf, _Float16* __restrict__ vT)
{
  const int K = 1024;
  __shared__ _Float16 Sm[16384];   // 32KB: A dbuf [0:8192), B dbuf [8192:16384)
  // T1 XCD swizzle: hw id -> logical id; XCD (hw&7) owns 128 contiguous
  // logical blocks. Decode: lm fastest -> 32 consecutive logicals share one
  // (z, n0) W panel; a 128-chunk never straddles z (128 divides 256/z).
  const int hw = blockIdx.x + 32 * blockIdx.y + 256 * blockIdx.z; // 0..1023
  const int logical = (hw & 7) * 128 + (hw >> 3);                 // bijective
  const int z = logical >> 8;
  const int m0 = (logical & 31) * 128;
  const int n0 = ((logical >> 5) & 7) * 128;
  const int wslot = (z==0)?0:(z==1)?3:(z==2)?1:2;   // wh order q,k,v,g
  const size_t woff = (size_t)wslot * (1024*1024);
  const float* bias = (z==0)?bqp:(z==1)?bgp:(z==2)?bkp:bvp;
  _Float16* outp = (z==0)?qf:(z==1)?gf:kf;          // z==3 handled separately
  const int t = threadIdx.x;
  const int lane = t & 63;
  const int w = t >> 6;
  const int wr = w >> 1, wc = w & 1;
  const int lm = lane & 15, quad = lane >> 4;
  // staging swizzle: lane covers row lin>>2, stores LDS block lane&3; fetch
  // global block (lane&3)^key, key = (row>>1)&3 = (lane>>3)&3
  const int scb = (((lane&3) ^ ((lane>>3)&3)))*8;
  // frag-read unswizzle key (row = ..*16 + lm -> (row>>1)&3 = (lm>>1)&3)
  const int rblk = ((quad ^ ((lm>>1)&3)))*8;

  auto stage = [&](int buf, int k0) {
    #pragma unroll
    for (int c=0;c<2;c++) {
      int lin = c*256 + t;
      int row = lin >> 2;
      size_t ga = (size_t)(m0+row)*K + k0 + scb;
      size_t gb = (size_t)(n0+row)*K + k0 + scb;
      int lo8 = (c*256 + w*64)*8;     // wave-uniform LDS chunk base (elems)
      ld_g2l_16(&xh[ga],        &Sm[buf*4096 + lo8]);
      ld_g2l_16(&wh[woff + gb], &Sm[8192 + buf*4096 + lo8]);
    }
  };

  f32x4 acc[4][4];
  #pragma unroll
  for (int i=0;i<4;i++)
    #pragma unroll
    for (int j=0;j<4;j++) acc[i][j] = (f32x4){0.f,0.f,0.f,0.f};

  stage(0, 0);
  __syncthreads();

  for (int k0 = 0; k0 < K; k0 += 32) {
    const int cur = (k0 >> 5) & 1;
    if (k0 + 32 < K) stage(cur ^ 1, k0 + 32);   // prefetch under MFMAs

    half8 ah[4];
    #pragma unroll
    for (int i=0;i<4;i++)
      ah[i] = *reinterpret_cast<const half8*>(&Sm[cur*4096 + (wr*64 + i*16 + lm)*32 + rblk]);
    #pragma unroll
    for (int j=0;j<4;j++) {
      half8 b = *reinterpret_cast<const half8*>(&Sm[8192 + cur*4096 + (wc*64 + j*16 + lm)*32 + rblk]);
      #pragma unroll
      for (int i=0;i<4;i++)
        acc[i][j] = __builtin_amdgcn_mfma_f32_16x16x32_f16(ah[i], b, acc[i][j], 0,0,0);
    }
    // single barrier/K-step: drains next-tile DMA (issued a full MFMA phase
    // ago) and retires all waves' reads of buf cur.
    __syncthreads();
  }

  // epilogue. C layout: col=lane&15, row=quad*4+reg
  if (z < 3) {
    #pragma unroll
    for (int j=0;j<4;j++) {
      int n = n0 + wc*64 + j*16 + lm;
      float bn = bias[n];
      #pragma unroll
      for (int i=0;i<4;i++) {
        int mb = m0 + wr*64 + i*16 + quad*4;
        #pragma unroll
        for (int r=0;r<4;r++)
          outp[(size_t)(mb+r)*PD + n] = (_Float16)(acc[i][j][r] + bn);
      }
    }
  } else {
    // v: transpose 128(token) x 128(n) tile through LDS, store coalesced.
    // Sm row = n_local (128 tokens/row); token-chunk c (8 elems) stored at
    // chunk position c ^ (n_local&15)  -> both sides swizzled, banks spread.
    #pragma unroll
    for (int j=0;j<4;j++) {
      int nl = wc*64 + j*16 + lm;
      float bn = bias[n0 + nl];
      #pragma unroll
      for (int i=0;i<4;i++) {
        int tb = wr*64 + i*16 + quad*4;   // token base, 8B-aligned in chunk
        half4v pv;
        #pragma unroll
        for (int r=0;r<4;r++) pv[r] = (_Float16)(acc[i][j][r] + bn);
        int sw = (tb >> 3) ^ (nl & 15);
        *reinterpret_cast<half4v*>(&Sm[nl*128 + sw*8 + (tb & 7)]) = pv;
      }
    }
    __syncthreads();
    // copy out: thread t -> vT row nl2 = t>>1, token-half (t&1)*64.
    // vT[bh][d][s]: contiguous along s -> half8 stores, fully coalesced.
    const int nl2 = t >> 1, co = (t & 1) * 8;
    const int hh = (n0 + nl2) >> 6, dd = (n0 + nl2) & 63;
    const int bb2 = m0 >> 11;
    const size_t vbase = ((size_t)((bb2*16 + hh)*64 + dd))*2048 + (m0 & 2047);
    #pragma unroll
    for (int c=0;c<8;c++) {
      int cc = co + c;
      half8 vv = *reinterpret_cast<const half8*>(&Sm[nl2*128 + ((cc ^ (nl2&15))<<3)]);
      *reinterpret_cast<half8*>(&vT[vbase + cc*8]) = vv;
    }
  }
}

// ---------------- flash attention v15 (reverted best: 55.6us) --------------
// R22: byte-for-byte revert to the R17/R19 kernel. R21's register
// P-transpose (permlane) was neutral-to-negative (57.5 vs 55.9) despite
// conflicts 3.1M->0 — flash is not LDS-throughput-bound; it sits in a
// latency/scheduling equilibrium only a deep-pipeline restructure would
// move. Structure: 8 waves x 16 Q rows, K+V LDS dbuf via DMA, one
// barrier/tile, T1 XCD bh-chunking, ones-MFMA lsum, exp2 softmax, setprio.
__global__ __launch_bounds__(512) void flash_attn(
    const _Float16* __restrict__ Qf,   // [B*S][1024] f16 (raw q)
    const _Float16* __restrict__ Gf,   // [B*S][1024] f16 (raw g)
    const _Float16* __restrict__ Kp,   // [B*S][1024] f16
    const _Float16* __restrict__ VT,   // [bh][64][2048] f16
    float* __restrict__ out)           // [B*S][1024] fp32
{
  __shared__ _Float16 Ks[2][64*64];    // K tile [n][d], swizzled, dbuf (16KB)
  __shared__ _Float16 Vts[2][64*64];   // V^T tile [d][n], swizzled, dbuf (16KB)
  __shared__ _Float16 Pss[8][16*72];   // per-wave P [m][n], stride 72 (18KB)
  const int t = threadIdx.x;
  const int lane = t & 63, w = t >> 6;
  const int lm = lane & 15, quad = lane >> 4;
  // T1 XCD swizzle: hw id -> logical id so each XCD gets 4 contiguous bh
  const int hw = blockIdx.x + gridDim.x * blockIdx.y;   // 0..511
  const int logical = (hw & 7) * 64 + (hw >> 3);        // bijective
  const int qblk = logical & 15;                        // q-tile index
  const int bh = logical >> 4;                          // head index 0..31
  const int b = bh >> 4, h = bh & 15;
  const int qb = qblk * 128 + w * 16;        // this wave's first Q row
  const size_t kbase = (size_t)b * PS * PD + (size_t)h * PHD;
  const size_t vtb = (size_t)bh * 64 * 2048;

  // staging: wave w covers rows w*8 + (lane>>3) -> 8 waves cover all 64
  // rows in ONE call per tensor. Lane fetches global block
  // (lane&7)^(lane>>3) so LDS block (lane&7) holds swizzled data.
  const int lrow = lane >> 3;
  const int lcb  = ((lane & 7) ^ lrow) * 8;
  // frag-read unswizzle: row&7 = lm&7; original blocks quad and quad+4
  const int kblk0 = ((quad     ^ (lm&7)))*8;
  const int kblk1 = (((quad+4) ^ (lm&7)))*8;

  // Q fragments: rows qb+lm, k = quad*8..+7 (+32); used as B operand.
  // qg = gelu(q*g) * log2e computed here in f32 (q,g rounded to f16 by proj)
  half8 qgf[2];
  {
    size_t qrow = kbase + (size_t)(qb + lm) * PD;
    half8 q0 = *reinterpret_cast<const half8*>(&Qf[qrow + quad*8]);
    half8 q1 = *reinterpret_cast<const half8*>(&Qf[qrow + 32 + quad*8]);
    half8 g0 = *reinterpret_cast<const half8*>(&Gf[qrow + quad*8]);
    half8 g1 = *reinterpret_cast<const half8*>(&Gf[qrow + 32 + quad*8]);
    #pragma unroll
    for (int e=0;e<8;e++) {
      float x0 = (float)q0[e] * (float)g0[e];
      float x1 = (float)q1[e] * (float)g1[e];
      float y0 = 0.5f * x0 * (1.0f + erff(x0 * 0.70710678118f));
      float y1 = 0.5f * x1 * (1.0f + erff(x1 * 0.70710678118f));
      qgf[0][e] = (_Float16)(y0 * 1.44269504f);
      qgf[1][e] = (_Float16)(y1 * 1.44269504f);
    }
  }

  // ones fragment for the row-sum MFMA (B operand, all 1.0h)
  half8 ones;
  #pragma unroll
  for (int e=0;e<8;e++) ones[e] = (_Float16)1.0f;

  f32x4 o[4];
  #pragma unroll
  for (int dc=0;dc<4;dc++) o[dc] = (f32x4){0.f,0.f,0.f,0.f};
  f32x4 o4 = (f32x4){0.f,0.f,0.f,0.f};   // row sums l (per Q-row quad*4+r)

  const _Float16* kgp = &Kp[kbase + (size_t)(w*8 + lrow)*PD + lcb];
  const _Float16* vgp = &VT[vtb + (size_t)(w*8 + lrow)*2048 + lcb];

  // QK accumulator C-init: -8*log2(e) => p = 2^s = e^(q.k - 8)
  const f32x4 sinit = {-11.54156036f, -11.54156036f, -11.54156036f, -11.54156036f};

  // prologue: stage tile 0 (K and V both via DMA), then one drain barrier
  ld_g2l_16(kgp, &Ks[0][(w*8)*64]);
  ld_g2l_16(vgp, &Vts[0][(w*8)*64]);
  __syncthreads();

  for (int kt = 0; kt < PS; kt += 64) {
    const int buf = (kt >> 6) & 1;
    const bool nx = (kt + 64) < PS;
    if (nx) {
      // prefetch next K and V tiles straight to LDS. buf^1's readers
      // retired at the end-of-iteration barrier of iter t-1.
      ld_g2l_16(kgp + (size_t)(kt+64)*PD, &Ks[buf^1][(w*8)*64]);
      ld_g2l_16(vgp + kt + 64,            &Vts[buf^1][(w*8)*64]);
    }

    // S^T = K @ QG^T : lane holds (n = ns*16 + quad*4 + r, m = lm)
    f32x4 s[4];
    __builtin_amdgcn_s_setprio(1);
    #pragma unroll
    for (int ns=0; ns<4; ns++) {
      const int rb = (ns*16 + lm)*64;
      half8 kf0 = *reinterpret_cast<const half8*>(&Ks[buf][rb + kblk0]);
      half8 kf1 = *reinterpret_cast<const half8*>(&Ks[buf][rb + kblk1]);
      f32x4 a = sinit;
      a = __builtin_amdgcn_mfma_f32_16x16x32_f16(kf0, qgf[0], a, 0,0,0);
      a = __builtin_amdgcn_mfma_f32_16x16x32_f16(kf1, qgf[1], a, 0,0,0);
      s[ns] = a;
    }
    __builtin_amdgcn_s_setprio(0);

    // p = clamp(2^s); pack 4 consecutive-n f16 -> one b64 store per ns
    #pragma unroll
    for (int ns=0; ns<4; ns++) {
      float p0 = fminf(__builtin_amdgcn_exp2f(s[ns][0]), 60000.0f);
      float p1 = fminf(__builtin_amdgcn_exp2f(s[ns][1]), 60000.0f);
      float p2 = fminf(__builtin_amdgcn_exp2f(s[ns][2]), 60000.0f);
      float p3 = fminf(__builtin_amdgcn_exp2f(s[ns][3]), 60000.0f);
      union { struct { fp16x2 a, b; } s2; half4v v; } u;
      u.s2.a = __builtin_amdgcn_cvt_pkrtz(p0, p1);
      u.s2.b = __builtin_amdgcn_cvt_pkrtz(p2, p3);
      *reinterpret_cast<half4v*>(&Pss[w][lm*72 + ns*16 + quad*4]) = u.v;
    }
    // per-wave LDS: compiler inserts lgkmcnt before readback; no barrier

    // O += P @ V (A = P[m][n] from LDS, B = V^T rows, swizzled blocks);
    // l += P @ 1 on the same pipe (ones B-fragment, no LDS read)
    half8 pa0 = *reinterpret_cast<const half8*>(&Pss[w][lm*72 + quad*8]);
    half8 pa1 = *reinterpret_cast<const half8*>(&Pss[w][lm*72 + 32 + quad*8]);
    __builtin_amdgcn_s_setprio(1);
    #pragma unroll
    for (int dc=0;dc<4;dc++) {
      const int vb = (dc*16 + lm)*64;
      half8 vb0 = *reinterpret_cast<const half8*>(&Vts[buf][vb + kblk0]);
      half8 vb1 = *reinterpret_cast<const half8*>(&Vts[buf][vb + kblk1]);
      o[dc] = __builtin_amdgcn_mfma_f32_16x16x32_f16(pa0, vb0, o[dc], 0,0,0);
      o[dc] = __builtin_amdgcn_mfma_f32_16x16x32_f16(pa1, vb1, o[dc], 0,0,0);
    }
    o4 = __builtin_amdgcn_mfma_f32_16x16x32_f16(pa0, ones, o4, 0,0,0);
    o4 = __builtin_amdgcn_mfma_f32_16x16x32_f16(pa1, ones, o4, 0,0,0);
    __builtin_amdgcn_s_setprio(0);

    // single barrier: drains this wave's next-tile DMAs (issued a full
    // compute phase ago) and retires all waves' reads of buf -> iter t+1
    // may read buf^1 and overwrite buf.
    __syncthreads();
  }

  // epilogue: o4[r] = l for Q-row quad*4+r (identical across lm) — no
  // cross-lane reduce needed.
  #pragma unroll
  for (int r=0;r<4;r++) {
    float invr = 1.0f / o4[r];
    int row = qb + quad*4 + r;
    size_t ob = kbase + (size_t)row * PD;
    #pragma unroll
    for (int dc=0;dc<4;dc++) {
      out[ob + dc*16 + lm] = o[dc][r] * invr;
    }
  }
}

extern "C" void kernel_launch(void* const* d_in, const int* in_sizes, int n_in,
                              void* d_out, int out_size, void* d_ws, size_t ws_size,
                              hipStream_t stream) {
  const float* x  = (const float*)d_in[0];
  const float* Wq = (const float*)d_in[1];
  const float* bq = (const float*)d_in[2];
  const float* Wk = (const float*)d_in[3];
  const float* bk = (const float*)d_in[4];
  const float* Wv = (const float*)d_in[5];
  const float* bv = (const float*)d_in[6];
  const float* Wg = (const float*)d_in[7];
  const float* bg = (const float*)d_in[8];
  float* out = (float*)d_out;

  char* ws = (char*)d_ws;
  const size_t MB = 1u << 20;
  // layout (MiB): 0 xh(8), 8 wh(8), 16 qf(8), 24 gf(8), 32 kf(8), 40 vT(8) = 48
  _Float16* xh = (_Float16*)(ws + 0*MB);
  _Float16* wh = (_Float16*)(ws + 8*MB);
  _Float16* qf = (_Float16*)(ws + 16*MB);
  _Float16* gf = (_Float16*)(ws + 24*MB);
  _Float16* kf = (_Float16*)(ws + 32*MB);
  _Float16* vT = (_Float16*)(ws + 40*MB);

  convert_all<<<dim3(2048, 2), 256, 0, stream>>>(x, Wq, Wk, Wv, Wg, xh, wh);

  proj_gemm<<<dim3(PM/128, PD/128, 4), 256, 0, stream>>>(
      xh, wh, bq, bg, bk, bv, qf, gf, kf, vT);

  flash_attn<<<dim3(PS/128, PB*PH), 512, 0, stream>>>(qf, gf, kf, vT, out);
}

// Round 13
// 183.580 us; speedup vs baseline: 1.0274x; 1.0274x over previous
//
#include <hip/hip_runtime.h>
#include <hip/hip_bf16.h>
#include <stdint.h>

// Problem constants
#define PB 2
#define PS 2048
#define PD 1024
#define PH 16
#define PHD 64
#define PM (PB*PS)   // 4096 rows

typedef _Float16 half8 __attribute__((ext_vector_type(8)));
typedef _Float16 half4v __attribute__((ext_vector_type(4)));
typedef __fp16   fp16x2 __attribute__((ext_vector_type(2)));
typedef float    f32x4 __attribute__((ext_vector_type(4)));

// async global->LDS, 16B per lane; LDS dst is wave-uniform base + lane*16.
// LESSON (R10/R18): never feed MFMA fragments from STRIDED global — R18's
// 4KB-stride V loads aliased every line to one L2 channel (flash 55->139us).
// LESSON (R21): flash is NOT LDS-throughput-bound — removing the P LDS
// round-trip via permlane (conflicts 3.1M->0, -6 LDS ops/tile) was neutral.
// LESSON (R22): XCD-chunking proj by (z, n-panel) thrashed x in L2 (+7.4us)
// — the default m-fastest round-robin keeps each XCD's x footprint small.
__device__ __forceinline__ void ld_g2l_16(const void* g, void* l) {
  __builtin_amdgcn_global_load_lds(
      (const __attribute__((address_space(1))) unsigned int*)g,
      (__attribute__((address_space(3))) unsigned int*)l, 16, 0, 0);
}

// ------------- fp32 -> fp16 convert, x and all 4 weights, one launch ------
// y=0: x (4.19M elems = 524288 half8); y=1: four 1M-elem weights -> wh slots
// q(0), k(1), v(2), g(3).
__global__ void convert_all(const float* __restrict__ x,
                            const float* __restrict__ w0, const float* __restrict__ w1,
                            const float* __restrict__ w2, const float* __restrict__ w3,
                            _Float16* __restrict__ xh, _Float16* __restrict__ wh) {
  int i = blockIdx.x * blockDim.x + threadIdx.x;
  const float* src;
  _Float16* dst;
  int idx;
  if (blockIdx.y == 0) {
    src = x; dst = xh; idx = i;
  } else {
    int wsel = i >> 17;            // 131072 half8 per weight
    idx = i & 131071;
    src = (wsel==0)?w0:(wsel==1)?w1:(wsel==2)?w2:w3;
    dst = wh + (size_t)wsel * 1048576;
  }
  float4 f0 = reinterpret_cast<const float4*>(src)[2*idx];
  float4 f1 = reinterpret_cast<const float4*>(src)[2*idx+1];
  half8 o;
  o[0]=(_Float16)f0.x; o[1]=(_Float16)f0.y; o[2]=(_Float16)f0.z; o[3]=(_Float16)f0.w;
  o[4]=(_Float16)f1.x; o[5]=(_Float16)f1.y; o[6]=(_Float16)f1.z; o[7]=(_Float16)f1.w;
  reinterpret_cast<half8*>(dst)[idx] = o;
}

// ------------------ projection GEMM: one weight per block ------------------
// R13: uniform 4-way split (z: 0=q,1=g,2=k,3=v), 128x128 tile, 1024 blocks.
// R20: (256,3) — the (256,4) cap only constrained the allocator (+3.5us).
// R23: REVERT of R22's XCD swizzle (+7.4us): concentrating one z per XCD
// made each XCD's resident blocks span all 32 m-tiles = the full 8MB x,
// thrashing the 4MB L2 on the x side. Default m-fastest dispatch keeps the
// concurrent x footprint per XCD small; W duplication is absorbed by L3.
// gelu(q*g) lives in flash's Q-load (q,g stored raw f16).
// z==3 (v): epilogue LDS-transpose (reuse staging LDS) -> coalesced half8
// vT stores. LDS XOR swizzle: row r stores 16B-block b at b^((r>>1)&3).
__global__ __launch_bounds__(256, 3) void proj_gemm(
    const _Float16* __restrict__ xh, const _Float16* __restrict__ wh,
    const float* __restrict__ bqp, const float* __restrict__ bgp,
    const float* __restrict__ bkp, const float* __restrict__ bvp,
    _Float16* __restrict__ qf, _Float16* __restrict__ gf,
    _Float16* __restrict__ kf, _Float16* __restrict__ vT)
{
  const int K = 1024;
  __shared__ _Float16 Sm[16384];   // 32KB: A dbuf [0:8192), B dbuf [8192:16384)
  const int z = blockIdx.z;
  const int wslot = (z==0)?0:(z==1)?3:(z==2)?1:2;   // wh order q,k,v,g
  const size_t woff = (size_t)wslot * (1024*1024);
  const float* bias = (z==0)?bqp:(z==1)?bgp:(z==2)?bkp:bvp;
  _Float16* outp = (z==0)?qf:(z==1)?gf:kf;          // z==3 handled separately
  const int m0 = blockIdx.x * 128;
  const int n0 = blockIdx.y * 128;
  const int t = threadIdx.x;
  const int lane = t & 63;
  const int w = t >> 6;
  const int wr = w >> 1, wc = w & 1;
  const int lm = lane & 15, quad = lane >> 4;
  // staging swizzle: lane covers row lin>>2, stores LDS block lane&3; fetch
  // global block (lane&3)^key, key = (row>>1)&3 = (lane>>3)&3
  const int scb = (((lane&3) ^ ((lane>>3)&3)))*8;
  // frag-read unswizzle key (row = ..*16 + lm -> (row>>1)&3 = (lm>>1)&3)
  const int rblk = ((quad ^ ((lm>>1)&3)))*8;

  auto stage = [&](int buf, int k0) {
    #pragma unroll
    for (int c=0;c<2;c++) {
      int lin = c*256 + t;
      int row = lin >> 2;
      size_t ga = (size_t)(m0+row)*K + k0 + scb;
      size_t gb = (size_t)(n0+row)*K + k0 + scb;
      int lo8 = (c*256 + w*64)*8;     // wave-uniform LDS chunk base (elems)
      ld_g2l_16(&xh[ga],        &Sm[buf*4096 + lo8]);
      ld_g2l_16(&wh[woff + gb], &Sm[8192 + buf*4096 + lo8]);
    }
  };

  f32x4 acc[4][4];
  #pragma unroll
  for (int i=0;i<4;i++)
    #pragma unroll
    for (int j=0;j<4;j++) acc[i][j] = (f32x4){0.f,0.f,0.f,0.f};

  stage(0, 0);
  __syncthreads();

  for (int k0 = 0; k0 < K; k0 += 32) {
    const int cur = (k0 >> 5) & 1;
    if (k0 + 32 < K) stage(cur ^ 1, k0 + 32);   // prefetch under MFMAs

    half8 ah[4];
    #pragma unroll
    for (int i=0;i<4;i++)
      ah[i] = *reinterpret_cast<const half8*>(&Sm[cur*4096 + (wr*64 + i*16 + lm)*32 + rblk]);
    #pragma unroll
    for (int j=0;j<4;j++) {
      half8 b = *reinterpret_cast<const half8*>(&Sm[8192 + cur*4096 + (wc*64 + j*16 + lm)*32 + rblk]);
      #pragma unroll
      for (int i=0;i<4;i++)
        acc[i][j] = __builtin_amdgcn_mfma_f32_16x16x32_f16(ah[i], b, acc[i][j], 0,0,0);
    }
    // single barrier/K-step: drains next-tile DMA (issued a full MFMA phase
    // ago) and retires all waves' reads of buf cur.
    __syncthreads();
  }

  // epilogue. C layout: col=lane&15, row=quad*4+reg
  if (z < 3) {
    #pragma unroll
    for (int j=0;j<4;j++) {
      int n = n0 + wc*64 + j*16 + lm;
      float bn = bias[n];
      #pragma unroll
      for (int i=0;i<4;i++) {
        int mb = m0 + wr*64 + i*16 + quad*4;
        #pragma unroll
        for (int r=0;r<4;r++)
          outp[(size_t)(mb+r)*PD + n] = (_Float16)(acc[i][j][r] + bn);
      }
    }
  } else {
    // v: transpose 128(token) x 128(n) tile through LDS, store coalesced.
    // Sm row = n_local (128 tokens/row); token-chunk c (8 elems) stored at
    // chunk position c ^ (n_local&15)  -> both sides swizzled, banks spread.
    #pragma unroll
    for (int j=0;j<4;j++) {
      int nl = wc*64 + j*16 + lm;
      float bn = bias[n0 + nl];
      #pragma unroll
      for (int i=0;i<4;i++) {
        int tb = wr*64 + i*16 + quad*4;   // token base, 8B-aligned in chunk
        half4v pv;
        #pragma unroll
        for (int r=0;r<4;r++) pv[r] = (_Float16)(acc[i][j][r] + bn);
        int sw = (tb >> 3) ^ (nl & 15);
        *reinterpret_cast<half4v*>(&Sm[nl*128 + sw*8 + (tb & 7)]) = pv;
      }
    }
    __syncthreads();
    // copy out: thread t -> vT row nl2 = t>>1, token-half (t&1)*64.
    // vT[bh][d][s]: contiguous along s -> half8 stores, fully coalesced.
    const int nl2 = t >> 1, co = (t & 1) * 8;
    const int hh = (n0 + nl2) >> 6, dd = (n0 + nl2) & 63;
    const int bb2 = m0 >> 11;
    const size_t vbase = ((size_t)((bb2*16 + hh)*64 + dd))*2048 + (m0 & 2047);
    #pragma unroll
    for (int c=0;c<8;c++) {
      int cc = co + c;
      half8 vv = *reinterpret_cast<const half8*>(&Sm[nl2*128 + ((cc ^ (nl2&15))<<3)]);
      *reinterpret_cast<half8*>(&vT[vbase + cc*8]) = vv;
    }
  }
}

// ---------------- flash attention v15 (best measured: 55.6us) --------------
// Structure: 8 waves x 16 Q rows, K+V LDS dbuf via DMA, one barrier/tile,
// T1 XCD bh-chunking (FETCH 74->16.4MB), ones-MFMA lsum, exp2 softmax with
// C-init=-8*log2e and qg pre-scaled by log2e, setprio around MFMA clusters.
// Established nulls: fetch (R17 timing), LDS volume (R15), bank conflicts
// (R21), direct-V from L2 (R18, -2.5x). Sits in a latency/scheduling
// equilibrium only a raw-barrier counted-vmcnt restructure might move.
__global__ __launch_bounds__(512) void flash_attn(
    const _Float16* __restrict__ Qf,   // [B*S][1024] f16 (raw q)
    const _Float16* __restrict__ Gf,   // [B*S][1024] f16 (raw g)
    const _Float16* __restrict__ Kp,   // [B*S][1024] f16
    const _Float16* __restrict__ VT,   // [bh][64][2048] f16
    float* __restrict__ out)           // [B*S][1024] fp32
{
  __shared__ _Float16 Ks[2][64*64];    // K tile [n][d], swizzled, dbuf (16KB)
  __shared__ _Float16 Vts[2][64*64];   // V^T tile [d][n], swizzled, dbuf (16KB)
  __shared__ _Float16 Pss[8][16*72];   // per-wave P [m][n], stride 72 (18KB)
  const int t = threadIdx.x;
  const int lane = t & 63, w = t >> 6;
  const int lm = lane & 15, quad = lane >> 4;
  // T1 XCD swizzle: hw id -> logical id so each XCD gets 4 contiguous bh
  const int hw = blockIdx.x + gridDim.x * blockIdx.y;   // 0..511
  const int logical = (hw & 7) * 64 + (hw >> 3);        // bijective
  const int qblk = logical & 15;                        // q-tile index
  const int bh = logical >> 4;                          // head index 0..31
  const int b = bh >> 4, h = bh & 15;
  const int qb = qblk * 128 + w * 16;        // this wave's first Q row
  const size_t kbase = (size_t)b * PS * PD + (size_t)h * PHD;
  const size_t vtb = (size_t)bh * 64 * 2048;

  // staging: wave w covers rows w*8 + (lane>>3) -> 8 waves cover all 64
  // rows in ONE call per tensor. Lane fetches global block
  // (lane&7)^(lane>>3) so LDS block (lane&7) holds swizzled data.
  const int lrow = lane >> 3;
  const int lcb  = ((lane & 7) ^ lrow) * 8;
  // frag-read unswizzle: row&7 = lm&7; original blocks quad and quad+4
  const int kblk0 = ((quad     ^ (lm&7)))*8;
  const int kblk1 = (((quad+4) ^ (lm&7)))*8;

  // Q fragments: rows qb+lm, k = quad*8..+7 (+32); used as B operand.
  // qg = gelu(q*g) * log2e computed here in f32 (q,g rounded to f16 by proj)
  half8 qgf[2];
  {
    size_t qrow = kbase + (size_t)(qb + lm) * PD;
    half8 q0 = *reinterpret_cast<const half8*>(&Qf[qrow + quad*8]);
    half8 q1 = *reinterpret_cast<const half8*>(&Qf[qrow + 32 + quad*8]);
    half8 g0 = *reinterpret_cast<const half8*>(&Gf[qrow + quad*8]);
    half8 g1 = *reinterpret_cast<const half8*>(&Gf[qrow + 32 + quad*8]);
    #pragma unroll
    for (int e=0;e<8;e++) {
      float x0 = (float)q0[e] * (float)g0[e];
      float x1 = (float)q1[e] * (float)g1[e];
      float y0 = 0.5f * x0 * (1.0f + erff(x0 * 0.70710678118f));
      float y1 = 0.5f * x1 * (1.0f + erff(x1 * 0.70710678118f));
      qgf[0][e] = (_Float16)(y0 * 1.44269504f);
      qgf[1][e] = (_Float16)(y1 * 1.44269504f);
    }
  }

  // ones fragment for the row-sum MFMA (B operand, all 1.0h)
  half8 ones;
  #pragma unroll
  for (int e=0;e<8;e++) ones[e] = (_Float16)1.0f;

  f32x4 o[4];
  #pragma unroll
  for (int dc=0;dc<4;dc++) o[dc] = (f32x4){0.f,0.f,0.f,0.f};
  f32x4 o4 = (f32x4){0.f,0.f,0.f,0.f};   // row sums l (per Q-row quad*4+r)

  const _Float16* kgp = &Kp[kbase + (size_t)(w*8 + lrow)*PD + lcb];
  const _Float16* vgp = &VT[vtb + (size_t)(w*8 + lrow)*2048 + lcb];

  // QK accumulator C-init: -8*log2(e) => p = 2^s = e^(q.k - 8)
  const f32x4 sinit = {-11.54156036f, -11.54156036f, -11.54156036f, -11.54156036f};

  // prologue: stage tile 0 (K and V both via DMA), then one drain barrier
  ld_g2l_16(kgp, &Ks[0][(w*8)*64]);
  ld_g2l_16(vgp, &Vts[0][(w*8)*64]);
  __syncthreads();

  for (int kt = 0; kt < PS; kt += 64) {
    const int buf = (kt >> 6) & 1;
    const bool nx = (kt + 64) < PS;
    if (nx) {
      // prefetch next K and V tiles straight to LDS. buf^1's readers
      // retired at the end-of-iteration barrier of iter t-1.
      ld_g2l_16(kgp + (size_t)(kt+64)*PD, &Ks[buf^1][(w*8)*64]);
      ld_g2l_16(vgp + kt + 64,            &Vts[buf^1][(w*8)*64]);
    }

    // S^T = K @ QG^T : lane holds (n = ns*16 + quad*4 + r, m = lm)
    f32x4 s[4];
    __builtin_amdgcn_s_setprio(1);
    #pragma unroll
    for (int ns=0; ns<4; ns++) {
      const int rb = (ns*16 + lm)*64;
      half8 kf0 = *reinterpret_cast<const half8*>(&Ks[buf][rb + kblk0]);
      half8 kf1 = *reinterpret_cast<const half8*>(&Ks[buf][rb + kblk1]);
      f32x4 a = sinit;
      a = __builtin_amdgcn_mfma_f32_16x16x32_f16(kf0, qgf[0], a, 0,0,0);
      a = __builtin_amdgcn_mfma_f32_16x16x32_f16(kf1, qgf[1], a, 0,0,0);
      s[ns] = a;
    }
    __builtin_amdgcn_s_setprio(0);

    // p = clamp(2^s); pack 4 consecutive-n f16 -> one b64 store per ns
    #pragma unroll
    for (int ns=0; ns<4; ns++) {
      float p0 = fminf(__builtin_amdgcn_exp2f(s[ns][0]), 60000.0f);
      float p1 = fminf(__builtin_amdgcn_exp2f(s[ns][1]), 60000.0f);
      float p2 = fminf(__builtin_amdgcn_exp2f(s[ns][2]), 60000.0f);
      float p3 = fminf(__builtin_amdgcn_exp2f(s[ns][3]), 60000.0f);
      union { struct { fp16x2 a, b; } s2; half4v v; } u;
      u.s2.a = __builtin_amdgcn_cvt_pkrtz(p0, p1);
      u.s2.b = __builtin_amdgcn_cvt_pkrtz(p2, p3);
      *reinterpret_cast<half4v*>(&Pss[w][lm*72 + ns*16 + quad*4]) = u.v;
    }
    // per-wave LDS: compiler inserts lgkmcnt before readback; no barrier

    // O += P @ V (A = P[m][n] from LDS, B = V^T rows, swizzled blocks);
    // l += P @ 1 on the same pipe (ones B-fragment, no LDS read)
    half8 pa0 = *reinterpret_cast<const half8*>(&Pss[w][lm*72 + quad*8]);
    half8 pa1 = *reinterpret_cast<const half8*>(&Pss[w][lm*72 + 32 + quad*8]);
    __builtin_amdgcn_s_setprio(1);
    #pragma unroll
    for (int dc=0;dc<4;dc++) {
      const int vb = (dc*16 + lm)*64;
      half8 vb0 = *reinterpret_cast<const half8*>(&Vts[buf][vb + kblk0]);
      half8 vb1 = *reinterpret_cast<const half8*>(&Vts[buf][vb + kblk1]);
      o[dc] = __builtin_amdgcn_mfma_f32_16x16x32_f16(pa0, vb0, o[dc], 0,0,0);
      o[dc] = __builtin_amdgcn_mfma_f32_16x16x32_f16(pa1, vb1, o[dc], 0,0,0);
    }
    o4 = __builtin_amdgcn_mfma_f32_16x16x32_f16(pa0, ones, o4, 0,0,0);
    o4 = __builtin_amdgcn_mfma_f32_16x16x32_f16(pa1, ones, o4, 0,0,0);
    __builtin_amdgcn_s_setprio(0);

    // single barrier: drains this wave's next-tile DMAs (issued a full
    // compute phase ago) and retires all waves' reads of buf -> iter t+1
    // may read buf^1 and overwrite buf.
    __syncthreads();
  }

  // epilogue: o4[r] = l for Q-row quad*4+r (identical across lm) — no
  // cross-lane reduce needed.
  #pragma unroll
  for (int r=0;r<4;r++) {
    float invr = 1.0f / o4[r];
    int row = qb + quad*4 + r;
    size_t ob = kbase + (size_t)row * PD;
    #pragma unroll
    for (int dc=0;dc<4;dc++) {
      out[ob + dc*16 + lm] = o[dc][r] * invr;
    }
  }
}

extern "C" void kernel_launch(void* const* d_in, const int* in_sizes, int n_in,
                              void* d_out, int out_size, void* d_ws, size_t ws_size,
                              hipStream_t stream) {
  const float* x  = (const float*)d_in[0];
  const float* Wq = (const float*)d_in[1];
  const float* bq = (const float*)d_in[2];
  const float* Wk = (const float*)d_in[3];
  const float* bk = (const float*)d_in[4];
  const float* Wv = (const float*)d_in[5];
  const float* bv = (const float*)d_in[6];
  const float* Wg = (const float*)d_in[7];
  const float* bg = (const float*)d_in[8];
  float* out = (float*)d_out;

  char* ws = (char*)d_ws;
  const size_t MB = 1u << 20;
  // layout (MiB): 0 xh(8), 8 wh(8), 16 qf(8), 24 gf(8), 32 kf(8), 40 vT(8) = 48
  _Float16* xh = (_Float16*)(ws + 0*MB);
  _Float16* wh = (_Float16*)(ws + 8*MB);
  _Float16* qf = (_Float16*)(ws + 16*MB);
  _Float16* gf = (_Float16*)(ws + 24*MB);
  _Float16* kf = (_Float16*)(ws + 32*MB);
  _Float16* vT = (_Float16*)(ws + 40*MB);

  convert_all<<<dim3(2048, 2), 256, 0, stream>>>(x, Wq, Wk, Wv, Wg, xh, wh);

  proj_gemm<<<dim3(PM/128, PD/128, 4), 256, 0, stream>>>(
      xh, wh, bq, bg, bk, bv, qf, gf, kf, vT);

  flash_attn<<<dim3(PS/128, PB*PH), 512, 0, stream>>>(qf, gf, kf, vT, out);
}

// Round 14
// 183.347 us; speedup vs baseline: 1.0287x; 1.0013x over previous
//
#include <hip/hip_runtime.h>
#include <hip/hip_bf16.h>
#include <stdint.h>

// Problem constants
#define PB 2
#define PS 2048
#define PD 1024
#define PH 16
#define PHD 64
#define PM (PB*PS)   // 4096 rows

typedef _Float16 half8 __attribute__((ext_vector_type(8)));
typedef _Float16 half4v __attribute__((ext_vector_type(4)));
typedef __fp16   fp16x2 __attribute__((ext_vector_type(2)));
typedef float    f32x4 __attribute__((ext_vector_type(4)));

// async global->LDS, 16B per lane; LDS dst is wave-uniform base + lane*16.
// LESSON (R10/R18): never feed MFMA fragments from STRIDED global — R18's
// 4KB-stride V loads aliased every line to one L2 channel (flash 55->139us).
// LESSON (R21): flash is NOT LDS-throughput-bound — removing the P LDS
// round-trip via permlane (conflicts 3.1M->0, -6 LDS ops/tile) was neutral.
// LESSON (R22): XCD-chunking proj by (z, n-panel) thrashed x in L2 (+7.4us)
// — the default m-fastest round-robin keeps each XCD's x footprint small.
__device__ __forceinline__ void ld_g2l_16(const void* g, void* l) {
  __builtin_amdgcn_global_load_lds(
      (const __attribute__((address_space(1))) unsigned int*)g,
      (__attribute__((address_space(3))) unsigned int*)l, 16, 0, 0);
}

// ------------- fp32 -> fp16 convert, x and all 4 weights, one launch ------
// y=0: x (4.19M elems = 524288 half8); y=1: four 1M-elem weights -> wh slots
// q(0), k(1), v(2), g(3).
__global__ void convert_all(const float* __restrict__ x,
                            const float* __restrict__ w0, const float* __restrict__ w1,
                            const float* __restrict__ w2, const float* __restrict__ w3,
                            _Float16* __restrict__ xh, _Float16* __restrict__ wh) {
  int i = blockIdx.x * blockDim.x + threadIdx.x;
  const float* src;
  _Float16* dst;
  int idx;
  if (blockIdx.y == 0) {
    src = x; dst = xh; idx = i;
  } else {
    int wsel = i >> 17;            // 131072 half8 per weight
    idx = i & 131071;
    src = (wsel==0)?w0:(wsel==1)?w1:(wsel==2)?w2:w3;
    dst = wh + (size_t)wsel * 1048576;
  }
  float4 f0 = reinterpret_cast<const float4*>(src)[2*idx];
  float4 f1 = reinterpret_cast<const float4*>(src)[2*idx+1];
  half8 o;
  o[0]=(_Float16)f0.x; o[1]=(_Float16)f0.y; o[2]=(_Float16)f0.z; o[3]=(_Float16)f0.w;
  o[4]=(_Float16)f1.x; o[5]=(_Float16)f1.y; o[6]=(_Float16)f1.z; o[7]=(_Float16)f1.w;
  reinterpret_cast<half8*>(dst)[idx] = o;
}

// ------------------ projection GEMM: one weight per block ------------------
// R13: uniform 4-way split (z: 0=q,1=g,2=k,3=v), 128x128 tile, 1024 blocks.
// R20: (256,3). R23: default dispatch order (no XCD swizzle — R22 thrashed
// x in L2). Single acc[4][4] + 32KB LDS, wave-level latency hiding.
// gelu(q*g) lives in flash's Q-load (q,g stored raw f16).
// z==3 (v): epilogue LDS-transpose (reuse staging LDS) -> coalesced half8
// vT stores. LDS XOR swizzle: row r stores 16B-block b at b^((r>>1)&3).
__global__ __launch_bounds__(256, 3) void proj_gemm(
    const _Float16* __restrict__ xh, const _Float16* __restrict__ wh,
    const float* __restrict__ bqp, const float* __restrict__ bgp,
    const float* __restrict__ bkp, const float* __restrict__ bvp,
    _Float16* __restrict__ qf, _Float16* __restrict__ gf,
    _Float16* __restrict__ kf, _Float16* __restrict__ vT)
{
  const int K = 1024;
  __shared__ _Float16 Sm[16384];   // 32KB: A dbuf [0:8192), B dbuf [8192:16384)
  const int z = blockIdx.z;
  const int wslot = (z==0)?0:(z==1)?3:(z==2)?1:2;   // wh order q,k,v,g
  const size_t woff = (size_t)wslot * (1024*1024);
  const float* bias = (z==0)?bqp:(z==1)?bgp:(z==2)?bkp:bvp;
  _Float16* outp = (z==0)?qf:(z==1)?gf:kf;          // z==3 handled separately
  const int m0 = blockIdx.x * 128;
  const int n0 = blockIdx.y * 128;
  const int t = threadIdx.x;
  const int lane = t & 63;
  const int w = t >> 6;
  const int wr = w >> 1, wc = w & 1;
  const int lm = lane & 15, quad = lane >> 4;
  // staging swizzle: lane covers row lin>>2, stores LDS block lane&3; fetch
  // global block (lane&3)^key, key = (row>>1)&3 = (lane>>3)&3
  const int scb = (((lane&3) ^ ((lane>>3)&3)))*8;
  // frag-read unswizzle key (row = ..*16 + lm -> (row>>1)&3 = (lm>>1)&3)
  const int rblk = ((quad ^ ((lm>>1)&3)))*8;

  auto stage = [&](int buf, int k0) {
    #pragma unroll
    for (int c=0;c<2;c++) {
      int lin = c*256 + t;
      int row = lin >> 2;
      size_t ga = (size_t)(m0+row)*K + k0 + scb;
      size_t gb = (size_t)(n0+row)*K + k0 + scb;
      int lo8 = (c*256 + w*64)*8;     // wave-uniform LDS chunk base (elems)
      ld_g2l_16(&xh[ga],        &Sm[buf*4096 + lo8]);
      ld_g2l_16(&wh[woff + gb], &Sm[8192 + buf*4096 + lo8]);
    }
  };

  f32x4 acc[4][4];
  #pragma unroll
  for (int i=0;i<4;i++)
    #pragma unroll
    for (int j=0;j<4;j++) acc[i][j] = (f32x4){0.f,0.f,0.f,0.f};

  stage(0, 0);
  __syncthreads();

  for (int k0 = 0; k0 < K; k0 += 32) {
    const int cur = (k0 >> 5) & 1;
    if (k0 + 32 < K) stage(cur ^ 1, k0 + 32);   // prefetch under MFMAs

    half8 ah[4];
    #pragma unroll
    for (int i=0;i<4;i++)
      ah[i] = *reinterpret_cast<const half8*>(&Sm[cur*4096 + (wr*64 + i*16 + lm)*32 + rblk]);
    #pragma unroll
    for (int j=0;j<4;j++) {
      half8 b = *reinterpret_cast<const half8*>(&Sm[8192 + cur*4096 + (wc*64 + j*16 + lm)*32 + rblk]);
      #pragma unroll
      for (int i=0;i<4;i++)
        acc[i][j] = __builtin_amdgcn_mfma_f32_16x16x32_f16(ah[i], b, acc[i][j], 0,0,0);
    }
    // single barrier/K-step: drains next-tile DMA (issued a full MFMA phase
    // ago) and retires all waves' reads of buf cur.
    __syncthreads();
  }

  // epilogue. C layout: col=lane&15, row=quad*4+reg
  if (z < 3) {
    #pragma unroll
    for (int j=0;j<4;j++) {
      int n = n0 + wc*64 + j*16 + lm;
      float bn = bias[n];
      #pragma unroll
      for (int i=0;i<4;i++) {
        int mb = m0 + wr*64 + i*16 + quad*4;
        #pragma unroll
        for (int r=0;r<4;r++)
          outp[(size_t)(mb+r)*PD + n] = (_Float16)(acc[i][j][r] + bn);
      }
    }
  } else {
    // v: transpose 128(token) x 128(n) tile through LDS, store coalesced.
    // Sm row = n_local (128 tokens/row); token-chunk c (8 elems) stored at
    // chunk position c ^ (n_local&15)  -> both sides swizzled, banks spread.
    #pragma unroll
    for (int j=0;j<4;j++) {
      int nl = wc*64 + j*16 + lm;
      float bn = bias[n0 + nl];
      #pragma unroll
      for (int i=0;i<4;i++) {
        int tb = wr*64 + i*16 + quad*4;   // token base, 8B-aligned in chunk
        half4v pv;
        #pragma unroll
        for (int r=0;r<4;r++) pv[r] = (_Float16)(acc[i][j][r] + bn);
        int sw = (tb >> 3) ^ (nl & 15);
        *reinterpret_cast<half4v*>(&Sm[nl*128 + sw*8 + (tb & 7)]) = pv;
      }
    }
    __syncthreads();
    // copy out: thread t -> vT row nl2 = t>>1, token-half (t&1)*64.
    // vT[bh][d][s]: contiguous along s -> half8 stores, fully coalesced.
    const int nl2 = t >> 1, co = (t & 1) * 8;
    const int hh = (n0 + nl2) >> 6, dd = (n0 + nl2) & 63;
    const int bb2 = m0 >> 11;
    const size_t vbase = ((size_t)((bb2*16 + hh)*64 + dd))*2048 + (m0 & 2047);
    #pragma unroll
    for (int c=0;c<8;c++) {
      int cc = co + c;
      half8 vv = *reinterpret_cast<const half8*>(&Sm[nl2*128 + ((cc ^ (nl2&15))<<3)]);
      *reinterpret_cast<half8*>(&vT[vbase + cc*8]) = vv;
    }
  }
}

// ---------------- flash attention v18 (att[2] software pipeline) -----------
// R24 (T15): v15's equilibrium (MfmaUtil 27, VALU 40, HBM 7.5, no pipe
// saturated; nulls on fetch/LDS-volume/conflicts) left one suspect: the
// per-tile serial chain QK -> wait(s) -> softmax -> P-roundtrip -> PV.
// Now iteration t computes QK(t+1) AND PV(t): P(t) carried in registers
// across the iteration, so the two MFMA groups are independent and issue
// back-to-back (PV fills QK-result latency), and softmax(t+1) moves off
// the MFMA path (its consumer is next iteration's PV). Numerics identical.
// Buffers: K dbuf (QK(t+1) reads Ks[(t+1)&1]; DMA K(t+2) -> Ks[t&1], last
// read one barrier ago). V TRIPLE buf (PV(t) reads Vts[t%3] while DMA
// V(t+2) -> Vts[(t+2)%3]; slot reuse 3 iters / 2 barriers apart). Prologue
// stages tiles 0,1; QK(0)+softmax(0); extra barrier before loop so iter-0's
// K(2) DMA can't overwrite Ks[0] under another wave's QK(0).
// LDS 16+24+18 = 58KB, 2 blocks/CU unchanged; one barrier/iter unchanged.
// Else = v15: 8 waves x 16 Q rows, T1 XCD bh-chunking, ones-MFMA lsum,
// exp2 softmax (C-init=-8*log2e, qg pre-scaled log2e), setprio.
__global__ __launch_bounds__(512) void flash_attn(
    const _Float16* __restrict__ Qf,   // [B*S][1024] f16 (raw q)
    const _Float16* __restrict__ Gf,   // [B*S][1024] f16 (raw g)
    const _Float16* __restrict__ Kp,   // [B*S][1024] f16
    const _Float16* __restrict__ VT,   // [bh][64][2048] f16
    float* __restrict__ out)           // [B*S][1024] fp32
{
  __shared__ _Float16 Ks[2][64*64];    // K tile [n][d], swizzled, dbuf (16KB)
  __shared__ _Float16 Vts[3][64*64];   // V^T tile [d][n], swizzled, 3buf (24KB)
  __shared__ _Float16 Pss[8][16*72];   // per-wave P [m][n], stride 72 (18KB)
  const int t = threadIdx.x;
  const int lane = t & 63, w = t >> 6;
  const int lm = lane & 15, quad = lane >> 4;
  // T1 XCD swizzle: hw id -> logical id so each XCD gets 4 contiguous bh
  const int hw = blockIdx.x + gridDim.x * blockIdx.y;   // 0..511
  const int logical = (hw & 7) * 64 + (hw >> 3);        // bijective
  const int qblk = logical & 15;                        // q-tile index
  const int bh = logical >> 4;                          // head index 0..31
  const int b = bh >> 4, h = bh & 15;
  const int qb = qblk * 128 + w * 16;        // this wave's first Q row
  const size_t kbase = (size_t)b * PS * PD + (size_t)h * PHD;
  const size_t vtb = (size_t)bh * 64 * 2048;

  // staging: wave w covers rows w*8 + (lane>>3) -> 8 waves cover all 64
  // rows in ONE call per tensor. Lane fetches global block
  // (lane&7)^(lane>>3) so LDS block (lane&7) holds swizzled data.
  const int lrow = lane >> 3;
  const int lcb  = ((lane & 7) ^ lrow) * 8;
  // frag-read unswizzle: row&7 = lm&7; original blocks quad and quad+4
  const int kblk0 = ((quad     ^ (lm&7)))*8;
  const int kblk1 = (((quad+4) ^ (lm&7)))*8;

  // Q fragments: rows qb+lm, k = quad*8..+7 (+32); used as B operand.
  // qg = gelu(q*g) * log2e computed here in f32 (q,g rounded to f16 by proj)
  half8 qgf[2];
  {
    size_t qrow = kbase + (size_t)(qb + lm) * PD;
    half8 q0 = *reinterpret_cast<const half8*>(&Qf[qrow + quad*8]);
    half8 q1 = *reinterpret_cast<const half8*>(&Qf[qrow + 32 + quad*8]);
    half8 g0 = *reinterpret_cast<const half8*>(&Gf[qrow + quad*8]);
    half8 g1 = *reinterpret_cast<const half8*>(&Gf[qrow + 32 + quad*8]);
    #pragma unroll
    for (int e=0;e<8;e++) {
      float x0 = (float)q0[e] * (float)g0[e];
      float x1 = (float)q1[e] * (float)g1[e];
      float y0 = 0.5f * x0 * (1.0f + erff(x0 * 0.70710678118f));
      float y1 = 0.5f * x1 * (1.0f + erff(x1 * 0.70710678118f));
      qgf[0][e] = (_Float16)(y0 * 1.44269504f);
      qgf[1][e] = (_Float16)(y1 * 1.44269504f);
    }
  }

  // ones fragment for the row-sum MFMA (B operand, all 1.0h)
  half8 ones;
  #pragma unroll
  for (int e=0;e<8;e++) ones[e] = (_Float16)1.0f;

  f32x4 o[4];
  #pragma unroll
  for (int dc=0;dc<4;dc++) o[dc] = (f32x4){0.f,0.f,0.f,0.f};
  f32x4 o4 = (f32x4){0.f,0.f,0.f,0.f};   // row sums l (per Q-row quad*4+r)

  const _Float16* kgp = &Kp[kbase + (size_t)(w*8 + lrow)*PD + lcb];
  const _Float16* vgp = &VT[vtb + (size_t)(w*8 + lrow)*2048 + lcb];

  // QK accumulator C-init: -8*log2(e) => p = 2^s = e^(q.k - 8)
  const f32x4 sinit = {-11.54156036f, -11.54156036f, -11.54156036f, -11.54156036f};

  // prologue: stage tiles 0 AND 1, drain; QK(0)+softmax(0) -> pa regs;
  // second barrier so iter-0's K(2) DMA can't overwrite Ks[0] while
  // another wave is still in QK(0).
  ld_g2l_16(kgp,                   &Ks[0][(w*8)*64]);
  ld_g2l_16(vgp,                   &Vts[0][(w*8)*64]);
  ld_g2l_16(kgp + (size_t)64*PD,   &Ks[1][(w*8)*64]);
  ld_g2l_16(vgp + 64,              &Vts[1][(w*8)*64]);
  __syncthreads();

  half8 pa0, pa1;   // P(t) A-fragments, carried across iterations
  {
    f32x4 s[4];
    __builtin_amdgcn_s_setprio(1);
    #pragma unroll
    for (int ns=0; ns<4; ns++) {
      const int rb = (ns*16 + lm)*64;
      half8 kf0 = *reinterpret_cast<const half8*>(&Ks[0][rb + kblk0]);
      half8 kf1 = *reinterpret_cast<const half8*>(&Ks[0][rb + kblk1]);
      f32x4 a = sinit;
      a = __builtin_amdgcn_mfma_f32_16x16x32_f16(kf0, qgf[0], a, 0,0,0);
      a = __builtin_amdgcn_mfma_f32_16x16x32_f16(kf1, qgf[1], a, 0,0,0);
      s[ns] = a;
    }
    __builtin_amdgcn_s_setprio(0);
    #pragma unroll
    for (int ns=0; ns<4; ns++) {
      float p0 = fminf(__builtin_amdgcn_exp2f(s[ns][0]), 60000.0f);
      float p1 = fminf(__builtin_amdgcn_exp2f(s[ns][1]), 60000.0f);
      float p2 = fminf(__builtin_amdgcn_exp2f(s[ns][2]), 60000.0f);
      float p3 = fminf(__builtin_amdgcn_exp2f(s[ns][3]), 60000.0f);
      union { struct { fp16x2 a, b; } s2; half4v v; } u;
      u.s2.a = __builtin_amdgcn_cvt_pkrtz(p0, p1);
      u.s2.b = __builtin_amdgcn_cvt_pkrtz(p2, p3);
      *reinterpret_cast<half4v*>(&Pss[w][lm*72 + ns*16 + quad*4]) = u.v;
    }
    pa0 = *reinterpret_cast<const half8*>(&Pss[w][lm*72 + quad*8]);
    pa1 = *reinterpret_cast<const half8*>(&Pss[w][lm*72 + 32 + quad*8]);
  }
  __syncthreads();

  for (int tt = 0; tt < 32; ++tt) {
    const bool nx1 = (tt + 1) < 32;
    const bool nx2 = (tt + 2) < 32;
    if (nx2) {
      // prefetch tile tt+2. Ks[tt&1]'s last reader was QK(tt) one barrier
      // ago; Vts[(tt+2)%3]'s last reader was PV(tt-1) one barrier ago.
      ld_g2l_16(kgp + (size_t)(tt+2)*64*PD, &Ks[tt & 1][(w*8)*64]);
      ld_g2l_16(vgp + (tt+2)*64,            &Vts[(tt+2)%3][(w*8)*64]);
    }

    // QK(tt+1): S^T = K @ QG^T, lane holds (n = ns*16+quad*4+r, m = lm)
    f32x4 s[4];
    if (nx1) {
      __builtin_amdgcn_s_setprio(1);
      #pragma unroll
      for (int ns=0; ns<4; ns++) {
        const int rb = (ns*16 + lm)*64;
        half8 kf0 = *reinterpret_cast<const half8*>(&Ks[(tt+1)&1][rb + kblk0]);
        half8 kf1 = *reinterpret_cast<const half8*>(&Ks[(tt+1)&1][rb + kblk1]);
        f32x4 a = sinit;
        a = __builtin_amdgcn_mfma_f32_16x16x32_f16(kf0, qgf[0], a, 0,0,0);
        a = __builtin_amdgcn_mfma_f32_16x16x32_f16(kf1, qgf[1], a, 0,0,0);
        s[ns] = a;
      }
      __builtin_amdgcn_s_setprio(0);
    }

    // PV(tt): O += P @ V with pa from registers (independent of QK above —
    // issues while QK results land); l += P @ 1 on the same pipe.
    __builtin_amdgcn_s_setprio(1);
    #pragma unroll
    for (int dc=0;dc<4;dc++) {
      const int vb = (dc*16 + lm)*64;
      half8 vb0 = *reinterpret_cast<const half8*>(&Vts[tt%3][vb + kblk0]);
      half8 vb1 = *reinterpret_cast<const half8*>(&Vts[tt%3][vb + kblk1]);
      o[dc] = __builtin_amdgcn_mfma_f32_16x16x32_f16(pa0, vb0, o[dc], 0,0,0);
      o[dc] = __builtin_amdgcn_mfma_f32_16x16x32_f16(pa1, vb1, o[dc], 0,0,0);
    }
    o4 = __builtin_amdgcn_mfma_f32_16x16x32_f16(pa0, ones, o4, 0,0,0);
    o4 = __builtin_amdgcn_mfma_f32_16x16x32_f16(pa1, ones, o4, 0,0,0);
    __builtin_amdgcn_s_setprio(0);

    // softmax(tt+1) -> Pss -> pa regs (consumer is NEXT iteration's PV;
    // overlaps with the PV MFMAs draining above)
    if (nx1) {
      #pragma unroll
      for (int ns=0; ns<4; ns++) {
        float p0 = fminf(__builtin_amdgcn_exp2f(s[ns][0]), 60000.0f);
        float p1 = fminf(__builtin_amdgcn_exp2f(s[ns][1]), 60000.0f);
        float p2 = fminf(__builtin_amdgcn_exp2f(s[ns][2]), 60000.0f);
        float p3 = fminf(__builtin_amdgcn_exp2f(s[ns][3]), 60000.0f);
        union { struct { fp16x2 a, b; } s2; half4v v; } u;
        u.s2.a = __builtin_amdgcn_cvt_pkrtz(p0, p1);
        u.s2.b = __builtin_amdgcn_cvt_pkrtz(p2, p3);
        *reinterpret_cast<half4v*>(&Pss[w][lm*72 + ns*16 + quad*4]) = u.v;
      }
      pa0 = *reinterpret_cast<const half8*>(&Pss[w][lm*72 + quad*8]);
      pa1 = *reinterpret_cast<const half8*>(&Pss[w][lm*72 + 32 + quad*8]);
    }

    // single barrier: drains this iter's tt+2 DMAs (read >=1 iter later)
    // and retires all waves' reads of Ks[(tt+1)&1] / Vts[tt%3] before
    // those slots are rewritten.
    __syncthreads();
  }

  // epilogue: o4[r] = l for Q-row quad*4+r (identical across lm) — no
  // cross-lane reduce needed.
  #pragma unroll
  for (int r=0;r<4;r++) {
    float invr = 1.0f / o4[r];
    int row = qb + quad*4 + r;
    size_t ob = kbase + (size_t)row * PD;
    #pragma unroll
    for (int dc=0;dc<4;dc++) {
      out[ob + dc*16 + lm] = o[dc][r] * invr;
    }
  }
}

extern "C" void kernel_launch(void* const* d_in, const int* in_sizes, int n_in,
                              void* d_out, int out_size, void* d_ws, size_t ws_size,
                              hipStream_t stream) {
  const float* x  = (const float*)d_in[0];
  const float* Wq = (const float*)d_in[1];
  const float* bq = (const float*)d_in[2];
  const float* Wk = (const float*)d_in[3];
  const float* bk = (const float*)d_in[4];
  const float* Wv = (const float*)d_in[5];
  const float* bv = (const float*)d_in[6];
  const float* Wg = (const float*)d_in[7];
  const float* bg = (const float*)d_in[8];
  float* out = (float*)d_out;

  char* ws = (char*)d_ws;
  const size_t MB = 1u << 20;
  // layout (MiB): 0 xh(8), 8 wh(8), 16 qf(8), 24 gf(8), 32 kf(8), 40 vT(8) = 48
  _Float16* xh = (_Float16*)(ws + 0*MB);
  _Float16* wh = (_Float16*)(ws + 8*MB);
  _Float16* qf = (_Float16*)(ws + 16*MB);
  _Float16* gf = (_Float16*)(ws + 24*MB);
  _Float16* kf = (_Float16*)(ws + 32*MB);
  _Float16* vT = (_Float16*)(ws + 40*MB);

  convert_all<<<dim3(2048, 2), 256, 0, stream>>>(x, Wq, Wk, Wv, Wg, xh, wh);

  proj_gemm<<<dim3(PM/128, PD/128, 4), 256, 0, stream>>>(
      xh, wh, bq, bg, bk, bv, qf, gf, kf, vT);

  flash_attn<<<dim3(PS/128, PB*PH), 512, 0, stream>>>(qf, gf, kf, vT, out);
}

// Round 15
// 179.399 us; speedup vs baseline: 1.0513x; 1.0220x over previous
//
#include <hip/hip_runtime.h>
#include <hip/hip_bf16.h>
#include <stdint.h>

// Problem constants
#define PB 2
#define PS 2048
#define PD 1024
#define PH 16
#define PHD 64
#define PM (PB*PS)   // 4096 rows

typedef _Float16 half8 __attribute__((ext_vector_type(8)));
typedef _Float16 half4v __attribute__((ext_vector_type(4)));
typedef __fp16   fp16x2 __attribute__((ext_vector_type(2)));
typedef float    f32x4 __attribute__((ext_vector_type(4)));

// async global->LDS, 16B per lane; LDS dst is wave-uniform base + lane*16.
// LESSON (R10/R18): never feed MFMA fragments from STRIDED global — R18's
// 4KB-stride V loads aliased every line to one L2 channel (flash 55->139us).
// LESSON (R21): flash is NOT LDS-throughput-bound — removing the P LDS
// round-trip via permlane (conflicts 3.1M->0, -6 LDS ops/tile) was neutral.
// LESSON (R22): XCD-chunking proj by (z, n-panel) thrashed x in L2 (+7.4us)
// — the default m-fastest round-robin keeps each XCD's x footprint small.
// LESSON (R24): the WIN lever on flash was pipelining the serial chain
// (QK(t+1) || PV(t), P carried in regs): 55.9 -> 53.4.
__device__ __forceinline__ void ld_g2l_16(const void* g, void* l) {
  __builtin_amdgcn_global_load_lds(
      (const __attribute__((address_space(1))) unsigned int*)g,
      (__attribute__((address_space(3))) unsigned int*)l, 16, 0, 0);
}

// ------------- fp32 -> fp16 convert, x and all 4 weights, one launch ------
// y=0: x (4.19M elems = 524288 half8); y=1: four 1M-elem weights -> wh slots
// q(0), k(1), v(2), g(3).
__global__ void convert_all(const float* __restrict__ x,
                            const float* __restrict__ w0, const float* __restrict__ w1,
                            const float* __restrict__ w2, const float* __restrict__ w3,
                            _Float16* __restrict__ xh, _Float16* __restrict__ wh) {
  int i = blockIdx.x * blockDim.x + threadIdx.x;
  const float* src;
  _Float16* dst;
  int idx;
  if (blockIdx.y == 0) {
    src = x; dst = xh; idx = i;
  } else {
    int wsel = i >> 17;            // 131072 half8 per weight
    idx = i & 131071;
    src = (wsel==0)?w0:(wsel==1)?w1:(wsel==2)?w2:w3;
    dst = wh + (size_t)wsel * 1048576;
  }
  float4 f0 = reinterpret_cast<const float4*>(src)[2*idx];
  float4 f1 = reinterpret_cast<const float4*>(src)[2*idx+1];
  half8 o;
  o[0]=(_Float16)f0.x; o[1]=(_Float16)f0.y; o[2]=(_Float16)f0.z; o[3]=(_Float16)f0.w;
  o[4]=(_Float16)f1.x; o[5]=(_Float16)f1.y; o[6]=(_Float16)f1.z; o[7]=(_Float16)f1.w;
  reinterpret_cast<half8*>(dst)[idx] = o;
}

// ------------------ projection GEMM: one weight per block ------------------
// R13: uniform 4-way split (z: 0=q,1=g,2=k,3=v), 128x128 tile, 1024 blocks.
// R20: (256,3). R23: default dispatch order (no XCD swizzle — R22 thrashed
// x in L2). Single acc[4][4] + 32KB LDS, wave-level latency hiding.
// gelu(q*g) lives in flash's Q-load (q,g stored raw f16).
// z==3 (v): epilogue LDS-transpose (reuse staging LDS) -> coalesced half8
// vT stores. LDS XOR swizzle: row r stores 16B-block b at b^((r>>1)&3).
__global__ __launch_bounds__(256, 3) void proj_gemm(
    const _Float16* __restrict__ xh, const _Float16* __restrict__ wh,
    const float* __restrict__ bqp, const float* __restrict__ bgp,
    const float* __restrict__ bkp, const float* __restrict__ bvp,
    _Float16* __restrict__ qf, _Float16* __restrict__ gf,
    _Float16* __restrict__ kf, _Float16* __restrict__ vT)
{
  const int K = 1024;
  __shared__ _Float16 Sm[16384];   // 32KB: A dbuf [0:8192), B dbuf [8192:16384)
  const int z = blockIdx.z;
  const int wslot = (z==0)?0:(z==1)?3:(z==2)?1:2;   // wh order q,k,v,g
  const size_t woff = (size_t)wslot * (1024*1024);
  const float* bias = (z==0)?bqp:(z==1)?bgp:(z==2)?bkp:bvp;
  _Float16* outp = (z==0)?qf:(z==1)?gf:kf;          // z==3 handled separately
  const int m0 = blockIdx.x * 128;
  const int n0 = blockIdx.y * 128;
  const int t = threadIdx.x;
  const int lane = t & 63;
  const int w = t >> 6;
  const int wr = w >> 1, wc = w & 1;
  const int lm = lane & 15, quad = lane >> 4;
  // staging swizzle: lane covers row lin>>2, stores LDS block lane&3; fetch
  // global block (lane&3)^key, key = (row>>1)&3 = (lane>>3)&3
  const int scb = (((lane&3) ^ ((lane>>3)&3)))*8;
  // frag-read unswizzle key (row = ..*16 + lm -> (row>>1)&3 = (lm>>1)&3)
  const int rblk = ((quad ^ ((lm>>1)&3)))*8;

  auto stage = [&](int buf, int k0) {
    #pragma unroll
    for (int c=0;c<2;c++) {
      int lin = c*256 + t;
      int row = lin >> 2;
      size_t ga = (size_t)(m0+row)*K + k0 + scb;
      size_t gb = (size_t)(n0+row)*K + k0 + scb;
      int lo8 = (c*256 + w*64)*8;     // wave-uniform LDS chunk base (elems)
      ld_g2l_16(&xh[ga],        &Sm[buf*4096 + lo8]);
      ld_g2l_16(&wh[woff + gb], &Sm[8192 + buf*4096 + lo8]);
    }
  };

  f32x4 acc[4][4];
  #pragma unroll
  for (int i=0;i<4;i++)
    #pragma unroll
    for (int j=0;j<4;j++) acc[i][j] = (f32x4){0.f,0.f,0.f,0.f};

  stage(0, 0);
  __syncthreads();

  for (int k0 = 0; k0 < K; k0 += 32) {
    const int cur = (k0 >> 5) & 1;
    if (k0 + 32 < K) stage(cur ^ 1, k0 + 32);   // prefetch under MFMAs

    half8 ah[4];
    #pragma unroll
    for (int i=0;i<4;i++)
      ah[i] = *reinterpret_cast<const half8*>(&Sm[cur*4096 + (wr*64 + i*16 + lm)*32 + rblk]);
    #pragma unroll
    for (int j=0;j<4;j++) {
      half8 b = *reinterpret_cast<const half8*>(&Sm[8192 + cur*4096 + (wc*64 + j*16 + lm)*32 + rblk]);
      #pragma unroll
      for (int i=0;i<4;i++)
        acc[i][j] = __builtin_amdgcn_mfma_f32_16x16x32_f16(ah[i], b, acc[i][j], 0,0,0);
    }
    // single barrier/K-step: drains next-tile DMA (issued a full MFMA phase
    // ago) and retires all waves' reads of buf cur.
    __syncthreads();
  }

  // epilogue. C layout: col=lane&15, row=quad*4+reg
  if (z < 3) {
    #pragma unroll
    for (int j=0;j<4;j++) {
      int n = n0 + wc*64 + j*16 + lm;
      float bn = bias[n];
      #pragma unroll
      for (int i=0;i<4;i++) {
        int mb = m0 + wr*64 + i*16 + quad*4;
        #pragma unroll
        for (int r=0;r<4;r++)
          outp[(size_t)(mb+r)*PD + n] = (_Float16)(acc[i][j][r] + bn);
      }
    }
  } else {
    // v: transpose 128(token) x 128(n) tile through LDS, store coalesced.
    // Sm row = n_local (128 tokens/row); token-chunk c (8 elems) stored at
    // chunk position c ^ (n_local&15)  -> both sides swizzled, banks spread.
    #pragma unroll
    for (int j=0;j<4;j++) {
      int nl = wc*64 + j*16 + lm;
      float bn = bias[n0 + nl];
      #pragma unroll
      for (int i=0;i<4;i++) {
        int tb = wr*64 + i*16 + quad*4;   // token base, 8B-aligned in chunk
        half4v pv;
        #pragma unroll
        for (int r=0;r<4;r++) pv[r] = (_Float16)(acc[i][j][r] + bn);
        int sw = (tb >> 3) ^ (nl & 15);
        *reinterpret_cast<half4v*>(&Sm[nl*128 + sw*8 + (tb & 7)]) = pv;
      }
    }
    __syncthreads();
    // copy out: thread t -> vT row nl2 = t>>1, token-half (t&1)*64.
    // vT[bh][d][s]: contiguous along s -> half8 stores, fully coalesced.
    const int nl2 = t >> 1, co = (t & 1) * 8;
    const int hh = (n0 + nl2) >> 6, dd = (n0 + nl2) & 63;
    const int bb2 = m0 >> 11;
    const size_t vbase = ((size_t)((bb2*16 + hh)*64 + dd))*2048 + (m0 & 2047);
    #pragma unroll
    for (int c=0;c<8;c++) {
      int cc = co + c;
      half8 vv = *reinterpret_cast<const half8*>(&Sm[nl2*128 + ((cc ^ (nl2&15))<<3)]);
      *reinterpret_cast<half8*>(&vT[vbase + cc*8]) = vv;
    }
  }
}

// ---------------- flash attention v19 (att[2] + V-frag register prefetch) --
// R24 gave 55.9->53.4 by computing QK(t+1) and PV(t) in one iteration with
// P carried in registers. R25: V-fragment register prefetch on top. V's
// triple buffer gives a 2-barrier slack K doesn't have: Vts[(tt+1)%3] is
// final from the end of iter tt-1, so iter tt reads tile tt+1's V frags
// into registers (overlapping softmax) and PV(tt+1) consumes pure regs.
// Removes 8 of 16 front-of-iteration LDS reads; PV issues immediately
// behind QK with zero LDS dependency. Race check: iter tt reads (tt+1)%3
// while DMA writes (tt+2)%3 — distinct; read slot drained one barrier ago.
// +32 VGPR (8x half8) -> ~90, still 4 waves/SIMD.
// Else = v18: K dbuf, V 3buf, one barrier/iter, T1 XCD bh-chunking,
// ones-MFMA lsum, exp2 softmax (C-init=-8*log2e, qg pre-scaled), setprio.
__global__ __launch_bounds__(512) void flash_attn(
    const _Float16* __restrict__ Qf,   // [B*S][1024] f16 (raw q)
    const _Float16* __restrict__ Gf,   // [B*S][1024] f16 (raw g)
    const _Float16* __restrict__ Kp,   // [B*S][1024] f16
    const _Float16* __restrict__ VT,   // [bh][64][2048] f16
    float* __restrict__ out)           // [B*S][1024] fp32
{
  __shared__ _Float16 Ks[2][64*64];    // K tile [n][d], swizzled, dbuf (16KB)
  __shared__ _Float16 Vts[3][64*64];   // V^T tile [d][n], swizzled, 3buf (24KB)
  __shared__ _Float16 Pss[8][16*72];   // per-wave P [m][n], stride 72 (18KB)
  const int t = threadIdx.x;
  const int lane = t & 63, w = t >> 6;
  const int lm = lane & 15, quad = lane >> 4;
  // T1 XCD swizzle: hw id -> logical id so each XCD gets 4 contiguous bh
  const int hw = blockIdx.x + gridDim.x * blockIdx.y;   // 0..511
  const int logical = (hw & 7) * 64 + (hw >> 3);        // bijective
  const int qblk = logical & 15;                        // q-tile index
  const int bh = logical >> 4;                          // head index 0..31
  const int b = bh >> 4, h = bh & 15;
  const int qb = qblk * 128 + w * 16;        // this wave's first Q row
  const size_t kbase = (size_t)b * PS * PD + (size_t)h * PHD;
  const size_t vtb = (size_t)bh * 64 * 2048;

  // staging: wave w covers rows w*8 + (lane>>3) -> 8 waves cover all 64
  // rows in ONE call per tensor. Lane fetches global block
  // (lane&7)^(lane>>3) so LDS block (lane&7) holds swizzled data.
  const int lrow = lane >> 3;
  const int lcb  = ((lane & 7) ^ lrow) * 8;
  // frag-read unswizzle: row&7 = lm&7; original blocks quad and quad+4
  const int kblk0 = ((quad     ^ (lm&7)))*8;
  const int kblk1 = (((quad+4) ^ (lm&7)))*8;

  // Q fragments: rows qb+lm, k = quad*8..+7 (+32); used as B operand.
  // qg = gelu(q*g) * log2e computed here in f32 (q,g rounded to f16 by proj)
  half8 qgf[2];
  {
    size_t qrow = kbase + (size_t)(qb + lm) * PD;
    half8 q0 = *reinterpret_cast<const half8*>(&Qf[qrow + quad*8]);
    half8 q1 = *reinterpret_cast<const half8*>(&Qf[qrow + 32 + quad*8]);
    half8 g0 = *reinterpret_cast<const half8*>(&Gf[qrow + quad*8]);
    half8 g1 = *reinterpret_cast<const half8*>(&Gf[qrow + 32 + quad*8]);
    #pragma unroll
    for (int e=0;e<8;e++) {
      float x0 = (float)q0[e] * (float)g0[e];
      float x1 = (float)q1[e] * (float)g1[e];
      float y0 = 0.5f * x0 * (1.0f + erff(x0 * 0.70710678118f));
      float y1 = 0.5f * x1 * (1.0f + erff(x1 * 0.70710678118f));
      qgf[0][e] = (_Float16)(y0 * 1.44269504f);
      qgf[1][e] = (_Float16)(y1 * 1.44269504f);
    }
  }

  // ones fragment for the row-sum MFMA (B operand, all 1.0h)
  half8 ones;
  #pragma unroll
  for (int e=0;e<8;e++) ones[e] = (_Float16)1.0f;

  f32x4 o[4];
  #pragma unroll
  for (int dc=0;dc<4;dc++) o[dc] = (f32x4){0.f,0.f,0.f,0.f};
  f32x4 o4 = (f32x4){0.f,0.f,0.f,0.f};   // row sums l (per Q-row quad*4+r)

  const _Float16* kgp = &Kp[kbase + (size_t)(w*8 + lrow)*PD + lcb];
  const _Float16* vgp = &VT[vtb + (size_t)(w*8 + lrow)*2048 + lcb];

  // QK accumulator C-init: -8*log2(e) => p = 2^s = e^(q.k - 8)
  const f32x4 sinit = {-11.54156036f, -11.54156036f, -11.54156036f, -11.54156036f};

  // prologue: stage tiles 0 AND 1, drain; QK(0)+softmax(0) -> pa regs and
  // V(0) frags -> vbr regs; second barrier so iter-0's K(2) DMA can't
  // overwrite Ks[0] while another wave is still in QK(0).
  ld_g2l_16(kgp,                   &Ks[0][(w*8)*64]);
  ld_g2l_16(vgp,                   &Vts[0][(w*8)*64]);
  ld_g2l_16(kgp + (size_t)64*PD,   &Ks[1][(w*8)*64]);
  ld_g2l_16(vgp + 64,              &Vts[1][(w*8)*64]);
  __syncthreads();

  half8 pa0, pa1;          // P(t) A-fragments, carried across iterations
  half8 vbr0[4], vbr1[4];  // V(t) B-fragments, carried across iterations
  {
    f32x4 s[4];
    __builtin_amdgcn_s_setprio(1);
    #pragma unroll
    for (int ns=0; ns<4; ns++) {
      const int rb = (ns*16 + lm)*64;
      half8 kf0 = *reinterpret_cast<const half8*>(&Ks[0][rb + kblk0]);
      half8 kf1 = *reinterpret_cast<const half8*>(&Ks[0][rb + kblk1]);
      f32x4 a = sinit;
      a = __builtin_amdgcn_mfma_f32_16x16x32_f16(kf0, qgf[0], a, 0,0,0);
      a = __builtin_amdgcn_mfma_f32_16x16x32_f16(kf1, qgf[1], a, 0,0,0);
      s[ns] = a;
    }
    __builtin_amdgcn_s_setprio(0);
    // V(0) fragments to registers (Vts[0] final since the drain barrier)
    #pragma unroll
    for (int dc=0;dc<4;dc++) {
      const int vb = (dc*16 + lm)*64;
      vbr0[dc] = *reinterpret_cast<const half8*>(&Vts[0][vb + kblk0]);
      vbr1[dc] = *reinterpret_cast<const half8*>(&Vts[0][vb + kblk1]);
    }
    #pragma unroll
    for (int ns=0; ns<4; ns++) {
      float p0 = fminf(__builtin_amdgcn_exp2f(s[ns][0]), 60000.0f);
      float p1 = fminf(__builtin_amdgcn_exp2f(s[ns][1]), 60000.0f);
      float p2 = fminf(__builtin_amdgcn_exp2f(s[ns][2]), 60000.0f);
      float p3 = fminf(__builtin_amdgcn_exp2f(s[ns][3]), 60000.0f);
      union { struct { fp16x2 a, b; } s2; half4v v; } u;
      u.s2.a = __builtin_amdgcn_cvt_pkrtz(p0, p1);
      u.s2.b = __builtin_amdgcn_cvt_pkrtz(p2, p3);
      *reinterpret_cast<half4v*>(&Pss[w][lm*72 + ns*16 + quad*4]) = u.v;
    }
    pa0 = *reinterpret_cast<const half8*>(&Pss[w][lm*72 + quad*8]);
    pa1 = *reinterpret_cast<const half8*>(&Pss[w][lm*72 + 32 + quad*8]);
  }
  __syncthreads();

  for (int tt = 0; tt < 32; ++tt) {
    const bool nx1 = (tt + 1) < 32;
    const bool nx2 = (tt + 2) < 32;
    if (nx2) {
      // prefetch tile tt+2. Ks[tt&1]'s last reader was QK(tt) one barrier
      // ago; Vts[(tt+2)%3]'s last readers retired >=1 barrier ago.
      ld_g2l_16(kgp + (size_t)(tt+2)*64*PD, &Ks[tt & 1][(w*8)*64]);
      ld_g2l_16(vgp + (tt+2)*64,            &Vts[(tt+2)%3][(w*8)*64]);
    }

    // QK(tt+1): S^T = K @ QG^T, lane holds (n = ns*16+quad*4+r, m = lm)
    f32x4 s[4];
    if (nx1) {
      __builtin_amdgcn_s_setprio(1);
      #pragma unroll
      for (int ns=0; ns<4; ns++) {
        const int rb = (ns*16 + lm)*64;
        half8 kf0 = *reinterpret_cast<const half8*>(&Ks[(tt+1)&1][rb + kblk0]);
        half8 kf1 = *reinterpret_cast<const half8*>(&Ks[(tt+1)&1][rb + kblk1]);
        f32x4 a = sinit;
        a = __builtin_amdgcn_mfma_f32_16x16x32_f16(kf0, qgf[0], a, 0,0,0);
        a = __builtin_amdgcn_mfma_f32_16x16x32_f16(kf1, qgf[1], a, 0,0,0);
        s[ns] = a;
      }
      __builtin_amdgcn_s_setprio(0);
    }

    // PV(tt): O += P @ V — ALL operands in registers (pa from last iter's
    // softmax, vbr from last iter's prefetch); issues behind QK with zero
    // LDS dependency. l += P @ 1 on the same pipe.
    __builtin_amdgcn_s_setprio(1);
    #pragma unroll
    for (int dc=0;dc<4;dc++) {
      o[dc] = __builtin_amdgcn_mfma_f32_16x16x32_f16(pa0, vbr0[dc], o[dc], 0,0,0);
      o[dc] = __builtin_amdgcn_mfma_f32_16x16x32_f16(pa1, vbr1[dc], o[dc], 0,0,0);
    }
    o4 = __builtin_amdgcn_mfma_f32_16x16x32_f16(pa0, ones, o4, 0,0,0);
    o4 = __builtin_amdgcn_mfma_f32_16x16x32_f16(pa1, ones, o4, 0,0,0);
    __builtin_amdgcn_s_setprio(0);

    if (nx1) {
      // V(tt+1) fragments -> registers for next iteration. Vts[(tt+1)%3]
      // final since end of iter tt-1; this iter's DMA writes (tt+2)%3.
      // Overlaps the softmax below.
      #pragma unroll
      for (int dc=0;dc<4;dc++) {
        const int vb = (dc*16 + lm)*64;
        vbr0[dc] = *reinterpret_cast<const half8*>(&Vts[(tt+1)%3][vb + kblk0]);
        vbr1[dc] = *reinterpret_cast<const half8*>(&Vts[(tt+1)%3][vb + kblk1]);
      }
      // softmax(tt+1) -> Pss -> pa regs (consumer is NEXT iteration's PV)
      #pragma unroll
      for (int ns=0; ns<4; ns++) {
        float p0 = fminf(__builtin_amdgcn_exp2f(s[ns][0]), 60000.0f);
        float p1 = fminf(__builtin_amdgcn_exp2f(s[ns][1]), 60000.0f);
        float p2 = fminf(__builtin_amdgcn_exp2f(s[ns][2]), 60000.0f);
        float p3 = fminf(__builtin_amdgcn_exp2f(s[ns][3]), 60000.0f);
        union { struct { fp16x2 a, b; } s2; half4v v; } u;
        u.s2.a = __builtin_amdgcn_cvt_pkrtz(p0, p1);
        u.s2.b = __builtin_amdgcn_cvt_pkrtz(p2, p3);
        *reinterpret_cast<half4v*>(&Pss[w][lm*72 + ns*16 + quad*4]) = u.v;
      }
      pa0 = *reinterpret_cast<const half8*>(&Pss[w][lm*72 + quad*8]);
      pa1 = *reinterpret_cast<const half8*>(&Pss[w][lm*72 + 32 + quad*8]);
    }

    // single barrier: drains this iter's tt+2 DMAs (read >=1 iter later)
    // and retires all waves' reads of Ks[(tt+1)&1] / Vts[(tt+1)%3] before
    // those slots are rewritten.
    __syncthreads();
  }

  // epilogue: o4[r] = l for Q-row quad*4+r (identical across lm) — no
  // cross-lane reduce needed.
  #pragma unroll
  for (int r=0;r<4;r++) {
    float invr = 1.0f / o4[r];
    int row = qb + quad*4 + r;
    size_t ob = kbase + (size_t)row * PD;
    #pragma unroll
    for (int dc=0;dc<4;dc++) {
      out[ob + dc*16 + lm] = o[dc][r] * invr;
    }
  }
}

extern "C" void kernel_launch(void* const* d_in, const int* in_sizes, int n_in,
                              void* d_out, int out_size, void* d_ws, size_t ws_size,
                              hipStream_t stream) {
  const float* x  = (const float*)d_in[0];
  const float* Wq = (const float*)d_in[1];
  const float* bq = (const float*)d_in[2];
  const float* Wk = (const float*)d_in[3];
  const float* bk = (const float*)d_in[4];
  const float* Wv = (const float*)d_in[5];
  const float* bv = (const float*)d_in[6];
  const float* Wg = (const float*)d_in[7];
  const float* bg = (const float*)d_in[8];
  float* out = (float*)d_out;

  char* ws = (char*)d_ws;
  const size_t MB = 1u << 20;
  // layout (MiB): 0 xh(8), 8 wh(8), 16 qf(8), 24 gf(8), 32 kf(8), 40 vT(8) = 48
  _Float16* xh = (_Float16*)(ws + 0*MB);
  _Float16* wh = (_Float16*)(ws + 8*MB);
  _Float16* qf = (_Float16*)(ws + 16*MB);
  _Float16* gf = (_Float16*)(ws + 24*MB);
  _Float16* kf = (_Float16*)(ws + 32*MB);
  _Float16* vT = (_Float16*)(ws + 40*MB);

  convert_all<<<dim3(2048, 2), 256, 0, stream>>>(x, Wq, Wk, Wv, Wg, xh, wh);

  proj_gemm<<<dim3(PM/128, PD/128, 4), 256, 0, stream>>>(
      xh, wh, bq, bg, bk, bv, qf, gf, kf, vT);

  flash_attn<<<dim3(PS/128, PB*PH), 512, 0, stream>>>(qf, gf, kf, vT, out);
}